// Round 1
// baseline (113.199 us; speedup 1.0000x reference)
//
#include <hip/hip_runtime.h>
#include <math.h>

#define DDIM 128
#define NB   8
#define NPT  50000
#define GROUPS_PER_BATCH (NPT / 8)          // 6250
#define NGROUPS (NB * GROUPS_PER_BATCH)     // 50000

// ---------------------------------------------------------------------------
// Setup kernel: per batch b, compute
//   qr[d] = q_real@Wq_r.T - q_imag@Wq_i.T + (bq_r - bq_i)
//   qi[d] = q_imag@Wq_r.T + q_real@Wq_i.T + (bq_r + bq_i)
//   u[e]  = sum_d qr[d]*Wk_r[d,e] + qi[d]*Wk_i[d,e]
//   v[e]  = sum_d qi[d]*Wk_r[d,e] - qr[d]*Wk_i[d,e]
//   c_ar  = qr·(bk_r - bk_i) + qi·(bk_r + bk_i)
//   c_ai  = qi·(bk_r - bk_i) - qr·(bk_r + bk_i)
// Then: ar = s*(hr·u + hi·v + c_ar), ai = s*(hr·v - hi·u + c_ai)
// ---------------------------------------------------------------------------
__global__ void setup_uv(const float* __restrict__ q_real,
                         const float* __restrict__ q_imag,
                         const float* __restrict__ Wq_r,
                         const float* __restrict__ Wq_i,
                         const float* __restrict__ bq_r,
                         const float* __restrict__ bq_i,
                         const float* __restrict__ Wk_r,
                         const float* __restrict__ Wk_i,
                         const float* __restrict__ bk_r,
                         const float* __restrict__ bk_i,
                         float* __restrict__ U,    // [NB][DDIM]
                         float* __restrict__ V,    // [NB][DDIM]
                         float* __restrict__ C)    // [NB][2]
{
    const int b = blockIdx.x;      // 0..7
    const int t = threadIdx.x;     // 0..127

    __shared__ float s_xr[DDIM], s_xi[DDIM], s_qr[DDIM], s_qi[DDIM];
    s_xr[t] = q_real[b * DDIM + t];
    s_xi[t] = q_imag[b * DDIM + t];
    __syncthreads();

    // thread t computes qr[t], qi[t]  (row t of Wq: y = x @ W.T)
    float qr = bq_r[t] - bq_i[t];
    float qi = bq_r[t] + bq_i[t];
    for (int e = 0; e < DDIM; ++e) {
        const float wr = Wq_r[t * DDIM + e];
        const float wi = Wq_i[t * DDIM + e];
        qr += s_xr[e] * wr - s_xi[e] * wi;
        qi += s_xi[e] * wr + s_xr[e] * wi;
    }
    s_qr[t] = qr;
    s_qi[t] = qi;
    __syncthreads();

    // thread t computes u[t], v[t]  (column t of Wk)
    float u = 0.f, v = 0.f;
    for (int d = 0; d < DDIM; ++d) {
        const float wr = Wk_r[d * DDIM + t];
        const float wi = Wk_i[d * DDIM + t];
        const float a = s_qr[d];
        const float c = s_qi[d];
        u += a * wr + c * wi;
        v += c * wr - a * wi;
    }
    U[b * DDIM + t] = u;
    V[b * DDIM + t] = v;

    if (t == 0) {
        float car = 0.f, cai = 0.f;
        for (int d = 0; d < DDIM; ++d) {
            const float bm = bk_r[d] - bk_i[d];
            const float bp = bk_r[d] + bk_i[d];
            car += s_qr[d] * bm + s_qi[d] * bp;
            cai += s_qi[d] * bm - s_qr[d] * bp;
        }
        C[b * 2 + 0] = car;
        C[b * 2 + 1] = cai;
    }
}

// ---------------------------------------------------------------------------
// Main kernel: one half-wave (32 lanes x float4) per row of h.
// Block = 256 threads = 4 waves = 8 rows per group. Grid-stride over groups.
// ---------------------------------------------------------------------------
__global__ __launch_bounds__(256) void power_kernel(
    const float4* __restrict__ h_real,   // [B*N][32] as float4
    const float4* __restrict__ h_imag,
    const float4* __restrict__ U4,       // [NB][32] as float4
    const float4* __restrict__ V4,
    const float*  __restrict__ C,        // [NB][2]
    float* __restrict__ out)             // [B*N]
{
    const int lane = threadIdx.x & 63;
    const int wave = threadIdx.x >> 6;   // 0..3
    const int half = lane >> 5;          // 0 or 1 (which row of the pair)
    const int e4   = lane & 31;          // float4 index within the row
    const float scaling = 0.08838834764831845f;  // 128^-0.5

    for (int g = blockIdx.x; g < NGROUPS; g += gridDim.x) {
        const int b = g / GROUPS_PER_BATCH;          // uniform per iteration
        const int p = g * 8 + wave * 2 + half;       // row index in [0, B*N)

        const float4 hr = h_real[p * 32 + e4];
        const float4 hi = h_imag[p * 32 + e4];
        const float4 u  = U4[b * 32 + e4];
        const float4 v  = V4[b * 32 + e4];

        // sA -> ar_pre partial (hr·u + hi·v); sB -> ai_pre partial (hr·v - hi·u)
        float sA = hr.x * u.x + hr.y * u.y + hr.z * u.z + hr.w * u.w
                 + hi.x * v.x + hi.y * v.y + hi.z * v.z + hi.w * v.w;
        float sB = hr.x * v.x + hr.y * v.y + hr.z * v.z + hr.w * v.w
                 - (hi.x * u.x + hi.y * u.y + hi.z * u.z + hi.w * u.w);

        // butterfly reduce within each 32-lane half (halves stay independent)
        #pragma unroll
        for (int m = 16; m >= 1; m >>= 1) {
            sA += __shfl_xor(sA, m, 32);
            sB += __shfl_xor(sB, m, 32);
        }

        if (e4 == 0) {
            const float car = C[b * 2 + 0];
            const float cai = C[b * 2 + 1];
            const float ar = scaling * (sA + car);
            const float ai = scaling * (sB + cai);
            const float mag = sqrtf(ar * ar + ai * ai);
            const float sc  = 10.0f * tanhf(mag) / fmaxf(mag, 1e-12f);
            const float cr  = sc * ar;
            const float ci  = -sc * ai;
            const float sr  = 1.0f / (1.0f + expf(-cr));
            const float si  = 1.0f / (1.0f + expf(-ci));
            float power = sr * sr + si * si;
            power = fminf(fmaxf(power, 0.0f), 1.0f);
            out[p] = power;
        }
    }
}

// ---------------------------------------------------------------------------
extern "C" void kernel_launch(void* const* d_in, const int* in_sizes, int n_in,
                              void* d_out, int out_size, void* d_ws, size_t ws_size,
                              hipStream_t stream) {
    const float* q_real = (const float*)d_in[0];
    const float* q_imag = (const float*)d_in[1];
    const float* h_real = (const float*)d_in[2];
    const float* h_imag = (const float*)d_in[3];
    const float* Wq_r   = (const float*)d_in[4];
    const float* Wq_i   = (const float*)d_in[5];
    const float* bq_r   = (const float*)d_in[6];
    const float* bq_i   = (const float*)d_in[7];
    const float* Wk_r   = (const float*)d_in[8];
    const float* Wk_i   = (const float*)d_in[9];
    const float* bk_r   = (const float*)d_in[10];
    const float* bk_i   = (const float*)d_in[11];

    float* out = (float*)d_out;
    float* ws  = (float*)d_ws;
    float* U = ws;                 // NB*DDIM floats
    float* V = ws + NB * DDIM;     // NB*DDIM floats
    float* C = ws + 2 * NB * DDIM; // NB*2 floats

    setup_uv<<<NB, DDIM, 0, stream>>>(q_real, q_imag, Wq_r, Wq_i, bq_r, bq_i,
                                      Wk_r, Wk_i, bk_r, bk_i, U, V, C);

    power_kernel<<<2048, 256, 0, stream>>>(
        (const float4*)h_real, (const float4*)h_imag,
        (const float4*)U, (const float4*)V, C, out);
}

// Round 2
// 92.876 us; speedup vs baseline: 1.2188x; 1.2188x over previous
//
#include <hip/hip_runtime.h>
#include <math.h>

#define DDIM 128
#define NB   8
#define NPT  50000
#define ROWS_TOTAL (NB * NPT)              // 400000
#define ROWS_PER_TILE 32                   // 256 threads / 8 lanes-per-row
#define NTILES (ROWS_TOTAL / ROWS_PER_TILE) // 12500
#define GRID_MAIN 1792                     // ~7 tiles/block, 7 blocks/CU

__device__ __forceinline__ float dot4(const float4 a, const float4 b) {
    return a.x * b.x + a.y * b.y + a.z * b.z + a.w * b.w;
}

// ---------------------------------------------------------------------------
// Setup kernel (per batch b):
//   qr[d] = q_real@Wq_r.T - q_imag@Wq_i.T + (bq_r - bq_i)
//   qi[d] = q_imag@Wq_r.T + q_real@Wq_i.T + (bq_r + bq_i)
//   u[e]  = sum_d qr[d]*Wk_r[d,e] + qi[d]*Wk_i[d,e]
//   v[e]  = sum_d qi[d]*Wk_r[d,e] - qr[d]*Wk_i[d,e]
//   c_ar  = qr·(bk_r - bk_i) + qi·(bk_r + bk_i)
//   c_ai  = qi·(bk_r - bk_i) - qr·(bk_r + bk_i)
// Then: ar = s*(hr·u + hi·v + c_ar), ai = s*(hr·v - hi·u + c_ai)
// ---------------------------------------------------------------------------
__global__ void setup_uv(const float* __restrict__ q_real,
                         const float* __restrict__ q_imag,
                         const float* __restrict__ Wq_r,
                         const float* __restrict__ Wq_i,
                         const float* __restrict__ bq_r,
                         const float* __restrict__ bq_i,
                         const float* __restrict__ Wk_r,
                         const float* __restrict__ Wk_i,
                         const float* __restrict__ bk_r,
                         const float* __restrict__ bk_i,
                         float* __restrict__ U,    // [NB][DDIM]
                         float* __restrict__ V,    // [NB][DDIM]
                         float* __restrict__ C)    // [NB][2]
{
    const int b = blockIdx.x;      // 0..7
    const int t = threadIdx.x;     // 0..127

    __shared__ float s_xr[DDIM], s_xi[DDIM], s_qr[DDIM], s_qi[DDIM];
    __shared__ float s_red[4];
    s_xr[t] = q_real[b * DDIM + t];
    s_xi[t] = q_imag[b * DDIM + t];
    __syncthreads();

    // thread t computes qr[t], qi[t]  (row t of Wq, vectorized float4)
    float qr = bq_r[t] - bq_i[t];
    float qi = bq_r[t] + bq_i[t];
    const float4* wr4 = (const float4*)Wq_r + t * 32;
    const float4* wi4 = (const float4*)Wq_i + t * 32;
    #pragma unroll 8
    for (int e4 = 0; e4 < 32; ++e4) {
        const float4 wr = wr4[e4];
        const float4 wi = wi4[e4];
        const float xr0 = s_xr[4*e4+0], xr1 = s_xr[4*e4+1];
        const float xr2 = s_xr[4*e4+2], xr3 = s_xr[4*e4+3];
        const float xi0 = s_xi[4*e4+0], xi1 = s_xi[4*e4+1];
        const float xi2 = s_xi[4*e4+2], xi3 = s_xi[4*e4+3];
        qr += (xr0*wr.x + xr1*wr.y + xr2*wr.z + xr3*wr.w)
            - (xi0*wi.x + xi1*wi.y + xi2*wi.z + xi3*wi.w);
        qi += (xi0*wr.x + xi1*wr.y + xi2*wr.z + xi3*wr.w)
            + (xr0*wi.x + xr1*wi.y + xr2*wi.z + xr3*wi.w);
    }
    s_qr[t] = qr;
    s_qi[t] = qi;
    __syncthreads();

    // thread t computes u[t], v[t] (column t of Wk; coalesced across lanes)
    float u = 0.f, v = 0.f;
    #pragma unroll 8
    for (int d = 0; d < DDIM; ++d) {
        const float wr = Wk_r[d * DDIM + t];
        const float wi = Wk_i[d * DDIM + t];
        const float a = s_qr[d];
        const float c = s_qi[d];
        u += a * wr + c * wi;
        v += c * wr - a * wi;
    }
    U[b * DDIM + t] = u;
    V[b * DDIM + t] = v;

    // c_ar / c_ai via parallel butterfly reduction over the 128 threads
    const float bm = bk_r[t] - bk_i[t];
    const float bp = bk_r[t] + bk_i[t];
    float car = s_qr[t] * bm + s_qi[t] * bp;
    float cai = s_qi[t] * bm - s_qr[t] * bp;
    #pragma unroll
    for (int m = 1; m < 64; m <<= 1) {
        car += __shfl_xor(car, m, 64);
        cai += __shfl_xor(cai, m, 64);
    }
    if ((t & 63) == 0) {
        s_red[(t >> 6) * 2 + 0] = car;
        s_red[(t >> 6) * 2 + 1] = cai;
    }
    __syncthreads();
    if (t == 0) {
        C[b * 2 + 0] = s_red[0] + s_red[2];
        C[b * 2 + 1] = s_red[1] + s_red[3];
    }
}

// ---------------------------------------------------------------------------
// Main kernel: 8 lanes per row, each lane loads 4 float4 of hr + 4 of hi
// (128 B in flight / lane). 3-step xor-butterfly reduce within 8-lane group.
// Block = 256 threads -> 32 rows per tile. Grid-stride over 12500 tiles.
// ---------------------------------------------------------------------------
__global__ __launch_bounds__(256) void power_kernel(
    const float4* __restrict__ h_real,   // [B*N][32] as float4
    const float4* __restrict__ h_imag,
    const float4* __restrict__ U4,       // [NB][32] as float4
    const float4* __restrict__ V4,
    const float*  __restrict__ C,        // [NB][2]
    float* __restrict__ out)             // [B*N]
{
    const int sub = threadIdx.x & 7;     // float4-lane within row
    const int rid = threadIdx.x >> 3;    // row within tile, 0..31
    const float scaling = 0.08838834764831845f;  // 128^-0.5

    for (int tile = blockIdx.x; tile < NTILES; tile += gridDim.x) {
        const int p = (tile << 5) + rid;     // row index in [0, B*N)
        const int b = p / NPT;

        const float4* hr = h_real + p * 32;
        const float4* hq = h_imag + p * 32;
        const float4* uu = U4 + b * 32;
        const float4* vv = V4 + b * 32;

        const float4 r0 = hr[sub +  0];
        const float4 r1 = hr[sub +  8];
        const float4 r2 = hr[sub + 16];
        const float4 r3 = hr[sub + 24];
        const float4 q0 = hq[sub +  0];
        const float4 q1 = hq[sub +  8];
        const float4 q2 = hq[sub + 16];
        const float4 q3 = hq[sub + 24];

        const float4 u0 = uu[sub +  0];
        const float4 u1 = uu[sub +  8];
        const float4 u2 = uu[sub + 16];
        const float4 u3 = uu[sub + 24];
        const float4 v0 = vv[sub +  0];
        const float4 v1 = vv[sub +  8];
        const float4 v2 = vv[sub + 16];
        const float4 v3 = vv[sub + 24];

        // sA partial: hr·u + hi·v ; sB partial: hr·v - hi·u
        float sA = dot4(r0,u0) + dot4(r1,u1) + dot4(r2,u2) + dot4(r3,u3)
                 + dot4(q0,v0) + dot4(q1,v1) + dot4(q2,v2) + dot4(q3,v3);
        float sB = dot4(r0,v0) + dot4(r1,v1) + dot4(r2,v2) + dot4(r3,v3)
                 - (dot4(q0,u0) + dot4(q1,u1) + dot4(q2,u2) + dot4(q3,u3));

        // butterfly reduce within each 8-lane group (all lanes get full sum)
        #pragma unroll
        for (int m = 1; m < 8; m <<= 1) {
            sA += __shfl_xor(sA, m, 8);
            sB += __shfl_xor(sB, m, 8);
        }

        // epilogue on all lanes (no divergence); store from lane 0 of group
        const float car = C[b * 2 + 0];
        const float cai = C[b * 2 + 1];
        const float ar = scaling * (sA + car);
        const float ai = scaling * (sB + cai);
        const float mag = sqrtf(ar * ar + ai * ai);
        const float sc  = 10.0f * tanhf(mag) / fmaxf(mag, 1e-12f);
        const float cr  = sc * ar;
        const float ci  = -sc * ai;
        const float sr  = 1.0f / (1.0f + expf(-cr));
        const float si  = 1.0f / (1.0f + expf(-ci));
        float power = sr * sr + si * si;
        power = fminf(fmaxf(power, 0.0f), 1.0f);
        if (sub == 0) out[p] = power;
    }
}

// ---------------------------------------------------------------------------
extern "C" void kernel_launch(void* const* d_in, const int* in_sizes, int n_in,
                              void* d_out, int out_size, void* d_ws, size_t ws_size,
                              hipStream_t stream) {
    const float* q_real = (const float*)d_in[0];
    const float* q_imag = (const float*)d_in[1];
    const float* h_real = (const float*)d_in[2];
    const float* h_imag = (const float*)d_in[3];
    const float* Wq_r   = (const float*)d_in[4];
    const float* Wq_i   = (const float*)d_in[5];
    const float* bq_r   = (const float*)d_in[6];
    const float* bq_i   = (const float*)d_in[7];
    const float* Wk_r   = (const float*)d_in[8];
    const float* Wk_i   = (const float*)d_in[9];
    const float* bk_r   = (const float*)d_in[10];
    const float* bk_i   = (const float*)d_in[11];

    float* out = (float*)d_out;
    float* ws  = (float*)d_ws;
    float* U = ws;                 // NB*DDIM floats
    float* V = ws + NB * DDIM;     // NB*DDIM floats
    float* C = ws + 2 * NB * DDIM; // NB*2 floats

    setup_uv<<<NB, DDIM, 0, stream>>>(q_real, q_imag, Wq_r, Wq_i, bq_r, bq_i,
                                      Wk_r, Wk_i, bk_r, bk_i, U, V, C);

    power_kernel<<<GRID_MAIN, 256, 0, stream>>>(
        (const float4*)h_real, (const float4*)h_imag,
        (const float4*)U, (const float4*)V, C, out);
}